// Round 1
// 273.901 us; speedup vs baseline: 1.0381x; 1.0381x over previous
//
#include <hip/hip_runtime.h>

// Problem constants (B=4, S=4096, D_MODEL=1024, H*Dk=H*Dv=1024)
#define M_TOT 16384
#define DM    1024

typedef unsigned short ushort_t;
typedef __bf16 bf16x8 __attribute__((ext_vector_type(8)));
typedef float  f32x4  __attribute__((ext_vector_type(4)));

__device__ __forceinline__ ushort_t f32_to_bf16(float f) {
    union { float f; unsigned u; } v; v.f = f;
    unsigned u = v.u;
    return (ushort_t)((u + 0x7fffu + ((u >> 16) & 1u)) >> 16);   // RNE
}
__device__ __forceinline__ float bf16_to_f32(ushort_t h) {
    union { unsigned u; float f; } v; v.u = ((unsigned)h) << 16;
    return v.f;
}

// async global->LDS, 16B per lane; LDS dest is wave-uniform base + lane*16
__device__ __forceinline__ void gload16(const ushort_t* g, ushort_t* l) {
    __builtin_amdgcn_global_load_lds(
        (const __attribute__((address_space(1))) unsigned int*)g,
        (__attribute__((address_space(3))) unsigned int*)l,
        16, 0, 0);
}

// ---------------- fused fp32 -> bf16 conversion ----------------
// x -> xb; Wv/Wg -> wcat with 16-row interleave (v rows p*32+r, g rows p*32+16+r)
// so that a 256-col GEMM tile pairs v/g fragments within one wave; Wo -> wob.
__global__ __launch_bounds__(256) void cvt_all(const float* __restrict__ x,
                                               const float* __restrict__ wv,
                                               const float* __restrict__ wg,
                                               const float* __restrict__ wo,
                                               ushort_t* __restrict__ xb,
                                               ushort_t* __restrict__ wcat,
                                               ushort_t* __restrict__ wob) {
    const long NX = (long)M_TOT * DM / 4, NW = (long)DM * DM / 4;
    long i = (long)blockIdx.x * 256 + threadIdx.x;     // float4 index
    const float* src; ushort_t* dst; long so, di;
    if (i < NX) {
        src = x; so = i; dst = xb; di = i;
    } else if (i < NX + NW) {
        long j = i - NX; src = wv; so = j;
        int row = (int)(j >> 8), c4 = (int)(j & 255);
        int orow = ((row >> 4) << 5) | (row & 15);
        dst = wcat; di = (long)orow * 256 + c4;
    } else if (i < NX + 2 * NW) {
        long j = i - NX - 2 * NW + NW; // = i - NX - NW
        j = i - NX - NW; src = wg; so = j;
        int row = (int)(j >> 8), c4 = (int)(j & 255);
        int orow = ((row >> 4) << 5) | 16 | (row & 15);
        dst = wcat; di = (long)orow * 256 + c4;
    } else {
        long j = i - NX - 2 * NW; src = wo; so = j; dst = wob; di = j;
    }
    const float4 v = ((const float4*)src)[so];
    ushort4 o;
    o.x = f32_to_bf16(v.x); o.y = f32_to_bf16(v.y);
    o.z = f32_to_bf16(v.z); o.w = f32_to_bf16(v.w);
    ((ushort4*)dst)[di] = o;
}

// ---------------- 256x256 counted-vmcnt pipelined GEMM ----------------
// BM=BN=256, BK=64, 512 threads (8 waves, 2M x 4N), per-wave 128x64, acc[8][4].
// LDS 128KB: fragment-tiled (1KB lane-linear frags), ring of 4 half-K-tile
// stage units (32KB each: A 16KB + B 16KB). Step u computes unit u, stages
// unit u+2. One s_barrier + s_waitcnt vmcnt(8) per step (drain 8->4->0 at end).
// EPI=0: silu-gate epilogue on interleaved v/g cols -> gated bf16 [M,1024]
// EPI=1: +bf16 residual -> pre bf16 [M,1024] (in-place over Xb is safe)
template<int EPI>
__global__ __launch_bounds__(512, 2) void gemm8p(
    const ushort_t* __restrict__ A,
    const ushort_t* __restrict__ B,
    const ushort_t* __restrict__ Xb,
    ushort_t* __restrict__ out,
    int nchunk)                       // grid/8 (XCD chunk size)
{
    extern __shared__ ushort_t lds[];   // 65536 ushorts = 128 KB

    const int flat = blockIdx.x;
    const int wgid = (flat & 7) * nchunk + (flat >> 3);   // bijective (grid%8==0)
    const int m0 = (wgid & 63) << 8;
    const int n0 = (wgid >> 6) << 8;

    const int tid  = threadIdx.x;
    const int w    = tid >> 6;         // wave 0..7
    const int l    = tid & 63;
    const int wm   = w >> 2;           // 0..1 (M)
    const int wn   = w & 3;            // 0..3 (N)
    const int fr   = l & 15;
    const int quad = l >> 4;

    f32x4 acc[8][4];
    const f32x4 vzero = {0.f, 0.f, 0.f, 0.f};
#pragma unroll
    for (int i = 0; i < 8; ++i)
#pragma unroll
        for (int j = 0; j < 4; ++j) acc[i][j] = vzero;

    // staging source bases (ushort idx): lane holds row (base + l&15), k-chunk (l>>4)*8
    int srcA[2], srcB[2];
#pragma unroll
    for (int h = 0; h < 2; ++h) {
        srcA[h] = (m0 + h * 128 + w * 16 + fr) * DM + (quad << 3);
        srcB[h] = (n0 + h * 128 + w * 16 + fr) * DM + (quad << 3);
    }

    // stage unit u2 = (ktS, cS): 2 A-loads + 2 B-loads per thread (h=0,1)
    auto stage = [&](int u2) {
        const int cS   = u2 & 1;
        const int bufS = (u2 >> 1) & 1;
        const int koff = (u2 >> 1) * 64 + cS * 32;
        const int dA   = bufS * 16384 + (cS * 8 + w) * 512;
#pragma unroll
        for (int h = 0; h < 2; ++h) {
            gload16(A + srcA[h] + koff, lds + dA + h * 8192);
            gload16(B + srcB[h] + koff, lds + 32768 + dA + h * 8192);
        }
    };

    stage(0); stage(1);   // prologue: first K-tile (units 0,1) in flight

    for (int u = 0; u < 32; ++u) {
        if (u < 30) {
            stage(u + 2);
            asm volatile("s_waitcnt vmcnt(8)" ::: "memory");   // unit u landed
        } else if (u == 30) {
            asm volatile("s_waitcnt vmcnt(4)" ::: "memory");
        } else {
            asm volatile("s_waitcnt vmcnt(0)" ::: "memory");
        }
        __builtin_amdgcn_s_barrier();

        const int buf = (u >> 1) & 1, c = u & 1;
        const int abase = buf * 16384 + wm * 8192 + c * 4096 + l * 8;
        const int bbase = 32768 + buf * 16384 + (wn >> 1) * 8192
                        + (c * 8 + (wn & 1) * 4) * 512 + l * 8;
        bf16x8 bfrag[4], afrag[8];
#pragma unroll
        for (int j = 0; j < 4; ++j) bfrag[j] = *(const bf16x8*)(lds + bbase + j * 512);
#pragma unroll
        for (int i = 0; i < 8; ++i) afrag[i] = *(const bf16x8*)(lds + abase + i * 512);

        __builtin_amdgcn_s_setprio(1);
#pragma unroll
        for (int j = 0; j < 4; ++j)
#pragma unroll
            for (int i = 0; i < 8; ++i)
                acc[i][j] = __builtin_amdgcn_mfma_f32_16x16x32_bf16(
                    afrag[i], bfrag[j], acc[i][j], 0, 0, 0);
        __builtin_amdgcn_s_setprio(0);
    }

    // epilogue; C/D layout: col = lane&15, row = quad*4 + r
    const int rowb = m0 + wm * 128;
    const int colb = n0 + wn * 64;
    if (EPI == 0) {
        // interleaved cat-cols: even frag = v, odd frag = g (same 16 v-cols)
#pragma unroll
        for (int i = 0; i < 8; ++i)
#pragma unroll
            for (int jp = 0; jp < 2; ++jp) {
                const int cb   = colb + jp * 32;
                const int vcol = ((cb >> 5) << 4) + fr;
#pragma unroll
                for (int r = 0; r < 4; ++r) {
                    const int row = rowb + i * 16 + quad * 4 + r;
                    float v = acc[i][2 * jp][r];
                    float g = acc[i][2 * jp + 1][r];
                    float gate = g / (1.0f + __expf(-g));   // silu
                    out[row * DM + vcol] = f32_to_bf16(v * gate);
                }
            }
    } else {
#pragma unroll
        for (int i = 0; i < 8; ++i)
#pragma unroll
            for (int j = 0; j < 4; ++j) {
                const int col = colb + j * 16 + fr;
#pragma unroll
                for (int r = 0; r < 4; ++r) {
                    const int row = rowb + i * 16 + quad * 4 + r;
                    float pre = acc[i][j][r] + bf16_to_f32(Xb[row * DM + col]);
                    out[row * DM + col] = f32_to_bf16(pre);
                }
            }
    }
}

// ---------------- LayerNorm over rows of 1024 ----------------
__global__ __launch_bounds__(256) void ln_rows(const ushort_t* __restrict__ pre,
                                               const float* __restrict__ gamma,
                                               const float* __restrict__ beta,
                                               float* __restrict__ out)
{
    const int row = blockIdx.x;
    const int tid = threadIdx.x;
    const int wave = tid >> 6, lane = tid & 63;

    ushort4 u = ((const ushort4*)(pre + row * DM))[tid];
    float p0 = bf16_to_f32(u.x), p1 = bf16_to_f32(u.y);
    float p2 = bf16_to_f32(u.z), p3 = bf16_to_f32(u.w);

    float s  = p0 + p1 + p2 + p3;
    float ss = p0 * p0 + p1 * p1 + p2 * p2 + p3 * p3;
#pragma unroll
    for (int off = 32; off > 0; off >>= 1) {
        s  += __shfl_down(s, off);
        ss += __shfl_down(ss, off);
    }
    __shared__ float red[8];
    __shared__ float mb[2];
    if (lane == 0) { red[wave] = s; red[4 + wave] = ss; }
    __syncthreads();
    if (tid == 0) {
        float S  = red[0] + red[1] + red[2] + red[3];
        float SS = red[4] + red[5] + red[6] + red[7];
        float mean = S * (1.0f / 1024.0f);
        float var  = SS * (1.0f / 1024.0f) - mean * mean;
        mb[0] = mean;
        mb[1] = rsqrtf(var + 1e-5f);
    }
    __syncthreads();
    const float mean = mb[0], rs = mb[1];

    float4 gm = ((const float4*)gamma)[tid];
    float4 bt = ((const float4*)beta)[tid];
    float4 o;
    o.x = (p0 - mean) * rs * gm.x + bt.x;
    o.y = (p1 - mean) * rs * gm.y + bt.y;
    o.z = (p2 - mean) * rs * gm.z + bt.z;
    o.w = (p3 - mean) * rs * gm.w + bt.w;
    ((float4*)(out + row * DM))[tid] = o;
}

// ---------------- launch ----------------
extern "C" void kernel_launch(void* const* d_in, const int* in_sizes, int n_in,
                              void* d_out, int out_size, void* d_ws, size_t ws_size,
                              hipStream_t stream) {
    // setup_inputs order: x, W_Q, W_K, W_V, W_g, W_alpha, W_O, ln_gamma, ln_beta
    const float* x     = (const float*)d_in[0];
    const float* WV    = (const float*)d_in[3];
    const float* WG    = (const float*)d_in[4];
    const float* WO    = (const float*)d_in[6];
    const float* gamma = (const float*)d_in[7];
    const float* beta  = (const float*)d_in[8];
    float* out = (float*)d_out;

    // ws layout: [0,32MB): x_bf16 (aliased as pre) | [32,64MB): gated
    //            [64,68MB): wcat (2048x1024 interleaved) | [68,70MB): wob
    char* ws = (char*)d_ws;
    ushort_t* xb    = (ushort_t*)ws;
    ushort_t* gated = (ushort_t*)(ws + (size_t)M_TOT * DM * 2);
    ushort_t* wcat  = (ushort_t*)(ws + (size_t)M_TOT * DM * 4);
    ushort_t* wob   = (ushort_t*)(ws + (size_t)M_TOT * DM * 4 + (size_t)2 * DM * DM * 2);
    ushort_t* pre   = xb;  // alias: in-place residual+store in gemm8p<1>

    static bool attr_set = false;
    if (!attr_set) {
        hipFuncSetAttribute((const void*)&gemm8p<0>,
                            hipFuncAttributeMaxDynamicSharedMemorySize, 131072);
        hipFuncSetAttribute((const void*)&gemm8p<1>,
                            hipFuncAttributeMaxDynamicSharedMemorySize, 131072);
        attr_set = true;
    }

    const int nCvt = (M_TOT * DM + 3 * DM * DM) / 4 / 256;
    cvt_all<<<nCvt, 256, 0, stream>>>(x, WV, WG, WO, xb, wcat, wob);

    // V&g cat-GEMM: M=16384, N=2048 -> 64 x 8 = 512 blocks
    gemm8p<0><<<512, 512, 131072, stream>>>(xb, wcat, nullptr, gated, 64);
    // O-proj: M=16384, N=1024 -> 64 x 4 = 256 blocks
    gemm8p<1><<<256, 512, 131072, stream>>>(gated, wob, xb, pre, 32);

    ln_rows<<<M_TOT, 256, 0, stream>>>(pre, gamma, beta, out);
}